// Round 10
// baseline (492.579 us; speedup 1.0000x reference)
//
#include <hip/hip_runtime.h>

#define ND   2048
#define BB   16384
#define NBLK 512

typedef unsigned short u16;
typedef unsigned int u32;
typedef __attribute__((ext_vector_type(8))) short short8;
typedef __attribute__((ext_vector_type(4))) float f32x4;
typedef u16 urow136[136];
typedef u16 urow33[33];

__device__ inline float bf2f(u16 u) {
    union { u32 i; float f; } v; v.i = ((u32)u) << 16; return v.f;
}
__device__ inline u16 f2bf(float f) {
    union { float f; u32 i; } v; v.f = f;
    u32 i = v.i + 0x7fffu + ((v.i >> 16) & 1u);
    return (u16)(i >> 16);
}
__device__ inline float seluf(float x) {
    const float sc = 1.0507009873554805f, al = 1.6732632423543772f;
    return x > 0.f ? sc * x : sc * al * expm1f(x);
}

#define NSEG 26

struct MG {
    const void* adj[3];
    const void* demb_raw;
    const void* src[NSEG]; int soff[NSEG]; int sn[NSEG];
    u16* canon;
    u16* ridx[3]; u32* rcnt[3];
    u16* cidx; u32* ccnt;
    const u16* demb; const u16* pemb;
    const u16* Wa1d; const u16* ba1d; const u16* Wa1p; const u16* ba1p;
    float* ko_d; float* qs_d; float* ko_p; float* qs_p;
    const u16* ts[6]; u16* W1T; u16* W2T; u16* WcTe; u16* WcTp;
    const u16* ba[3]; const u16* bb[3]; u16* b_e; u16* b_p;
    float* csd; float* csp;
    const u16* avgidx[2]; const u32* avgcnt[2]; const u16* avgemb[2]; u16* avgout[2];
    const u16* sidx[2]; const u32* scnt[2];
    const float* sko[2]; const float* sqs[2];
    const u16* sw2[2]; const u16* sb2[2];
    const u16* semb[2]; const float* scs[2];
    u16* sout[2];
    const u16* gA[2]; const u16* gBT[2]; u16* gC[2]; const u16* gbias[2];
    const int* di; const int* dr;
    const u16* mb1_; const u16* mb2_;
    const u16* wpred; const u16* bpred; const int* labels;
    float* out; float* lossacc;
    u32* bar;
};

// software grid barrier: monotonic counter, all NBLK blocks co-resident
// (guaranteed by __launch_bounds__(256,2) + grid == 2 blocks/CU * 256 CUs).
__device__ inline void gbar(u32* bar, u32 target) {
    __syncthreads();
    if (threadIdx.x == 0) {
        __threadfence();                      // release: flush this block's writes
        atomicAdd(bar, 1u);
        while (atomicAdd(bar, 0u) < target)   // coherent RMW read
            __builtin_amdgcn_s_sleep(2);
        __threadfence();                      // acquire
    }
    __syncthreads();
}

// ---------------- init: zero counters (separate dispatch, pre-mega) --------
__global__ void initk(u32* __restrict__ cntT, float* __restrict__ lossacc,
                      u32* __restrict__ bar) {
    int tid = threadIdx.x;
    #pragma unroll
    for (int i = 0; i < 8; i++) cntT[i * 256 + tid] = 0u;
    if (tid == 0) { lossacc[0] = 0.f; bar[0] = 0u; }
}

__global__ __launch_bounds__(256, 2) void mega(MG g) {
    int tid = threadIdx.x;
    int bid = blockIdx.x;
    int lane = tid & 63, wv = tid >> 6;

    __shared__ __align__(16) char Lraw[52352];

    // ===== S0: dtype flag (per-block, deterministic) =======================
    bool f32;
    {
        int* redf = (int*)Lraw;
        const u16* p6 = (const u16*)g.demb_raw;
        int sane = 0;
        #pragma unroll
        for (int i = 0; i < 2; i++) {
            u16 u = p6[4 * tid + 2 * i];
            int e = (u >> 7) & 0xFF;
            if (u == 0 || (e >= 0x66 && e <= 0x8C)) sane++;
        }
        redf[tid] = sane;
        __syncthreads();
        for (int o = 128; o > 0; o >>= 1) {
            if (tid < o) redf[tid] += redf[tid + o];
            __syncthreads();
        }
        f32 = redf[0] < 300;
        __syncthreads();
    }

    // ===== S1: conversion + CSR row lists ==================================
    for (int vb = bid; vb < 3200; vb += NBLK) {
        if (vb < 1536) {
            int m = vb >> 9;
            int r0 = (vb & 511) * 4;
            u32* lcnt = (u32*)Lraw;
            if (tid < 4) lcnt[tid] = 0;
            __syncthreads();
            float v[4][8];
            int c0 = tid * 8;
            if (f32) {
                #pragma unroll
                for (int rr = 0; rr < 4; rr++) {
                    const float4* p = (const float4*)((const float*)g.adj[m] +
                                                      (size_t)(r0 + rr) * 2048 + c0);
                    float4 x = p[0], y = p[1];
                    v[rr][0] = x.x; v[rr][1] = x.y; v[rr][2] = x.z; v[rr][3] = x.w;
                    v[rr][4] = y.x; v[rr][5] = y.y; v[rr][6] = y.z; v[rr][7] = y.w;
                }
            } else {
                #pragma unroll
                for (int rr = 0; rr < 4; rr++) {
                    const uint4* p = (const uint4*)((const u16*)g.adj[m] +
                                                    (size_t)(r0 + rr) * 2048 + c0);
                    uint4 x = p[0];
                    u32 u[4] = {x.x, x.y, x.z, x.w};
                    #pragma unroll
                    for (int i = 0; i < 4; i++) {
                        v[rr][2 * i + 0] = (u[i] & 0xffffu) ? 1.f : 0.f;
                        v[rr][2 * i + 1] = (u[i] >> 16)     ? 1.f : 0.f;
                    }
                }
            }
            #pragma unroll
            for (int rr = 0; rr < 4; rr++) {
                int cnt = 0;
                #pragma unroll
                for (int i = 0; i < 8; i++) cnt += (v[rr][i] != 0.f) ? 1 : 0;
                int pfx = cnt;
                #pragma unroll
                for (int o = 1; o < 64; o <<= 1) {
                    int s = __shfl_up(pfx, o, 64);
                    if (lane >= o) pfx += s;
                }
                int wtot = __shfl(pfx, 63, 64);
                u32 wb = 0;
                if (lane == 0) wb = atomicAdd(&lcnt[rr], (u32)wtot);
                wb = __shfl((int)wb, 0, 64);
                int o = (int)wb + pfx - cnt;
                u16* ridxp = g.ridx[m] + (size_t)(r0 + rr) * 2048;
                #pragma unroll
                for (int i = 0; i < 8; i++) {
                    if (v[rr][i] != 0.f) ridxp[o++] = (u16)(c0 + i);
                }
            }
            __syncthreads();
            if (tid < 4) g.rcnt[m][r0 + tid] = lcnt[tid];
        } else {
            int idx = vb - 1536;
            int seg = idx >> 6, xb = idx & 63;
            int n = g.sn[seg];
            const void* s = g.src[seg];
            u16* d = g.canon + g.soff[seg];
            int nw = n >> 1;
            if (f32) {
                const float2* sf = (const float2*)s;
                u32* dw = (u32*)d;
                for (int i = xb * 256 + tid; i < nw; i += 16384) {
                    float2 vv = sf[i];
                    dw[i] = (u32)f2bf(vv.x) | ((u32)f2bf(vv.y) << 16);
                }
            } else {
                const u32* sw = (const u32*)s;
                u32* dw = (u32*)d;
                for (int i = xb * 256 + tid; i < nw; i += 16384) dw[i] = sw[i];
            }
            if ((n & 1) && xb == 0 && tid == 0)
                d[n - 1] = f32 ? f2bf(((const float*)s)[n - 1]) : ((const u16*)s)[n - 1];
        }
        __syncthreads();
    }
    gbar(g.bar, NBLK * 1);

    // ===== S2: prep ========================================================
    for (int vb = bid; vb < 4196; vb += NBLK) {
        if (vb < 4) {
            float* st0 = (float*)Lraw;
            float* st1 = (float*)(Lraw + 1024);
            int m = vb >> 1, half = vb & 1;
            const u16* e = m ? g.pemb : g.demb;
            int c2 = tid & 31, rg = tid >> 5;
            int dbase = half * 64;
            float s0 = 0.f, s1 = 0.f;
            for (int it = 0; it < 256; it++) {
                int row = it * 8 + rg;
                u32 v = *(const u32*)(e + (size_t)row * 128 + dbase + c2 * 2);
                s0 += bf2f((u16)(v & 0xffffu));
                s1 += bf2f((u16)(v >> 16));
            }
            st0[tid] = s0; st1[tid] = s1;
            __syncthreads();
            if (tid < 32) {
                float a0 = 0.f, a1 = 0.f;
                #pragma unroll
                for (int gg = 0; gg < 8; gg++) { a0 += st0[gg * 32 + tid]; a1 += st1[gg * 32 + tid]; }
                float* cs = m ? g.csp : g.csd;
                cs[dbase + tid * 2 + 0] = a0;
                cs[dbase + tid * 2 + 1] = a1;
            }
            if (tid < 64) {
                int d = dbase + tid;
                if (m == 0)
                    g.b_e[d] = f2bf(bf2f(g.ba[0][d]) + bf2f(g.ba[1][d]) + bf2f(g.ba[2][d]));
                else
                    g.b_p[d] = f2bf(bf2f(g.bb[0][d]) + bf2f(g.bb[1][d]) + bf2f(g.bb[2][d]));
            }
        } else if (vb < 2052) {
            int r = vb - 4;
            int n = (int)g.rcnt[0][r];
            const u16* row = g.ridx[0] + (size_t)r * 2048;
            for (int i = tid; i < n; i += 256) {
                int cc = (int)row[i];
                u32 q = atomicAdd(&g.ccnt[cc], 1u);
                g.cidx[(size_t)cc * 2048 + q] = (u16)r;
            }
        } else if (vb < 3076) {
            int id = vb - 2052;
            int task = id >> 9, blk = id & 511;
            int grp = lane >> 4, dim = lane & 15;
            int r = blk * 4 + wv;
            const u16* idx = g.avgidx[task] + (size_t)r * 2048;
            int nnz = (int)g.avgcnt[task][r];
            const u16* emb = g.avgemb[task];
            float acc[8];
            #pragma unroll
            for (int t = 0; t < 8; t++) acc[t] = 0.f;
            for (int base = 0; base < nnz; base += 64) {
                int i = base + lane;
                int j = (i < nnz) ? (int)idx[i] : 0;
                int cend = min(64, nnz - base);
                #pragma unroll 4
                for (int k4 = 0; k4 < cend; k4 += 4) {
                    int kk = k4 + grp;
                    int jk = __shfl(j, kk, 64);
                    float wk = (base + kk < nnz) ? 1.f : 0.f;
                    const uint4* pp = (const uint4*)((const char*)emb + jk * 256 + dim * 16);
                    uint4 vv = *pp;
                    u32 u[4] = {vv.x, vv.y, vv.z, vv.w};
                    #pragma unroll
                    for (int cc = 0; cc < 4; cc++) {
                        acc[2 * cc + 0] = fmaf(wk, bf2f((u16)(u[cc] & 0xffffu)), acc[2 * cc + 0]);
                        acc[2 * cc + 1] = fmaf(wk, bf2f((u16)(u[cc] >> 16)), acc[2 * cc + 1]);
                    }
                }
            }
            #pragma unroll
            for (int t = 0; t < 8; t++) {
                acc[t] += __shfl_xor(acc[t], 32, 64);
                acc[t] += __shfl_xor(acc[t], 16, 64);
            }
            if (grp == 0) {
                float sc = 1.f / ((float)nnz + 1e-8f);
                float v[8];
                #pragma unroll
                for (int t = 0; t < 8; t++) v[t] = acc[t] * sc;
                uint4 pk;
                pk.x = (u32)f2bf(v[0]) | ((u32)f2bf(v[1]) << 16);
                pk.y = (u32)f2bf(v[2]) | ((u32)f2bf(v[3]) << 16);
                pk.z = (u32)f2bf(v[4]) | ((u32)f2bf(v[5]) << 16);
                pk.w = (u32)f2bf(v[6]) | ((u32)f2bf(v[7]) << 16);
                *(uint4*)(g.avgout[task] + (size_t)r * 256 + dim * 8) = pk;
            }
        } else if (vb < 4100) {
            float* sx = (float*)Lraw;
            float* sred = (float*)(Lraw + 1024);
            u16* Wl = (u16*)(Lraw + 2048);
            int blk = vb - 3076;
            int m = blk >> 8;
            int r0 = (blk & 255) * 8;
            const u16* src; const u16* W; const u16* bias; float* out;
            switch (m) {
                case 0:  src = g.pemb; W = g.Wa1d;            bias = nullptr; out = g.ko_d; break;
                case 1:  src = g.demb; W = g.Wa1d + 128 * 32; bias = g.ba1d;  out = g.qs_d; break;
                case 2:  src = g.demb; W = g.Wa1p;            bias = nullptr; out = g.ko_p; break;
                default: src = g.pemb; W = g.Wa1p + 128 * 32; bias = g.ba1p;  out = g.qs_p; break;
            }
            {
                const uint4* wsrc = (const uint4*)W;
                uint4* wdst = (uint4*)Wl;
                #pragma unroll
                for (int i = 0; i < 2; i++) wdst[i * 256 + tid] = wsrc[i * 256 + tid];
            }
            __syncthreads();
            int sub = tid >> 7, t = tid & 127;
            int a = t & 31, part = t >> 5;
            #pragma unroll 1
            for (int rp = 0; rp < 4; rp++) {
                int row = r0 + rp * 2 + sub;
                sx[sub * 128 + t] = bf2f(src[(size_t)row * 128 + t]);
                __syncthreads();
                float s = 0.f;
                #pragma unroll
                for (int k = 0; k < 32; k++)
                    s += sx[sub * 128 + part * 32 + k] * bf2f(Wl[(part * 32 + k) * 32 + a]);
                sred[sub * 128 + t] = s;
                __syncthreads();
                if (part == 0) {
                    float tt = sred[sub * 128 + a] + sred[sub * 128 + a + 32] +
                               sred[sub * 128 + a + 64] + sred[sub * 128 + a + 96];
                    if (bias) tt += bf2f(bias[a]);
                    out[(size_t)row * 32 + a] = tt;
                }
                __syncthreads();
            }
        } else {
            urow33* stile = (urow33*)Lraw;
            int id = vb - 4100;
            int z = id >> 4, rem = id & 15;
            int c0 = (rem & 3) * 32, r0 = (rem >> 2) * 32;
            const u16* in = g.ts[z];
            u16* out; int ldo, ooff;
            switch (z) {
                case 0:  out = g.W1T;  ldo = 128; ooff = 0;   break;
                case 1:  out = g.W2T;  ldo = 128; ooff = 0;   break;
                case 2:  out = g.WcTe; ldo = 256; ooff = 0;   break;
                case 3:  out = g.WcTe; ldo = 256; ooff = 128; break;
                case 4:  out = g.WcTp; ldo = 256; ooff = 0;   break;
                default: out = g.WcTp; ldo = 256; ooff = 128; break;
            }
            int tx = tid & 31, ty = tid >> 5;
            int x = c0 + tx;
            for (int i = ty; i < 32; i += 8)
                stile[i][tx] = in[(size_t)(r0 + i) * 128 + x];
            __syncthreads();
            int rr = r0 + tx;
            for (int i = ty; i < 32; i += 8)
                out[(size_t)(c0 + i) * ldo + ooff + rr] = stile[tx][i];
        }
        __syncthreads();
    }
    gbar(g.bar, NBLK * 2);

    // ===== S3: sparse attention aggregation ================================
    for (int vb = bid; vb < 1024; vb += NBLK) {
        int task = vb >> 9, blk = vb & 511;
        int grp = lane >> 4, dim = lane & 15;
        int r = blk * 4 + wv;
        const u16* idx = g.sidx[task] + (size_t)r * 2048;
        int nnz = (int)g.scnt[task][r];
        const u16* emb = g.semb[task];
        const float* ko = g.sko[task];

        float qsr[32], w2h[32];
        {
            const float4* qp = (const float4*)(g.sqs[task] + (size_t)r * 32);
            #pragma unroll
            for (int i = 0; i < 8; i++) {
                float4 v = qp[i];
                qsr[4 * i + 0] = v.x; qsr[4 * i + 1] = v.y;
                qsr[4 * i + 2] = v.z; qsr[4 * i + 3] = v.w;
            }
            #pragma unroll
            for (int i = 0; i < 32; i++) w2h[i] = bf2f(g.sw2[task][i]);
        }
        float b2v = bf2f(g.sb2[task][0]);

        float acc[8];
        #pragma unroll
        for (int t = 0; t < 8; t++) acc[t] = 0.f;
        float wsuml = 0.f;

        for (int base = 0; base < nnz; base += 64) {
            int i = base + lane;
            float w = 0.f;
            int j = 0;
            if (i < nnz) {
                j = (int)idx[i];
                const float4* kp = (const float4*)(ko + (size_t)j * 32);
                float s = 0.f;
                #pragma unroll
                for (int q = 0; q < 8; q++) {
                    float4 kv = kp[q];
                    s += fmaxf(qsr[4 * q + 0] + kv.x, 0.f) * w2h[4 * q + 0];
                    s += fmaxf(qsr[4 * q + 1] + kv.y, 0.f) * w2h[4 * q + 1];
                    s += fmaxf(qsr[4 * q + 2] + kv.z, 0.f) * w2h[4 * q + 2];
                    s += fmaxf(qsr[4 * q + 3] + kv.w, 0.f) * w2h[4 * q + 3];
                }
                w = __expf(fmaxf(s + b2v, 0.f)) - 1.f;
                wsuml += w;
            }
            int cend = min(64, nnz - base);
            #pragma unroll 4
            for (int k4 = 0; k4 < cend; k4 += 4) {
                int kk = k4 + grp;
                float wk = __shfl(w, kk, 64);
                int jk = __shfl(j, kk, 64);
                const uint4* pp = (const uint4*)((const char*)emb + jk * 256 + dim * 16);
                uint4 vv = *pp;
                u32 u[4] = {vv.x, vv.y, vv.z, vv.w};
                #pragma unroll
                for (int cc = 0; cc < 4; cc++) {
                    acc[2 * cc + 0] = fmaf(wk, bf2f((u16)(u[cc] & 0xffffu)), acc[2 * cc + 0]);
                    acc[2 * cc + 1] = fmaf(wk, bf2f((u16)(u[cc] >> 16)), acc[2 * cc + 1]);
                }
            }
        }
        #pragma unroll
        for (int t = 0; t < 8; t++) {
            acc[t] += __shfl_xor(acc[t], 32, 64);
            acc[t] += __shfl_xor(acc[t], 16, 64);
        }
        #pragma unroll
        for (int o = 32; o > 0; o >>= 1) wsuml += __shfl_xor(wsuml, o, 64);

        if (grp == 0) {
            float sc = 1.f / (2048.f + wsuml);
            const float* cs = g.scs[task] + dim * 8;
            float v[8];
            #pragma unroll
            for (int t = 0; t < 8; t++) v[t] = (cs[t] + acc[t]) * sc;
            uint4 pk;
            pk.x = (u32)f2bf(v[0]) | ((u32)f2bf(v[1]) << 16);
            pk.y = (u32)f2bf(v[2]) | ((u32)f2bf(v[3]) << 16);
            pk.z = (u32)f2bf(v[4]) | ((u32)f2bf(v[5]) << 16);
            pk.w = (u32)f2bf(v[6]) | ((u32)f2bf(v[7]) << 16);
            *(uint4*)(g.sout[task] + (size_t)r * 256 + dim * 8) = pk;
        }
    }
    gbar(g.bar, NBLK * 3);

    // ===== S4: combine GEMMs (bias + SELU) =================================
    for (int vb = bid; vb < 256; vb += NBLK) {
        urow136* As = (urow136*)Lraw;
        urow136* Bs = (urow136*)(Lraw + 4352);
        int z = vb >> 7, bx = vb & 127;
        const u16* A = g.gA[z];
        const u16* BT = g.gBT[z];
        int mrow = lane & 15, quad = lane >> 4;
        int m0 = bx * 16;
        int c0 = wv * 32;
        int sr = tid >> 4, sk = (tid & 15) * 8;
        f32x4 acc0 = {0.f, 0.f, 0.f, 0.f}, acc1 = {0.f, 0.f, 0.f, 0.f};

        short8 ra, rb[8];
        auto ldstage = [&](int kb) {
            ra = *(const short8*)(A + (size_t)(m0 + sr) * 256 + kb + sk);
            const u16* bbase = BT + (size_t)sr * 256 + kb + sk;
            #pragma unroll
            for (int i = 0; i < 8; i++)
                rb[i] = *(const short8*)(bbase + (size_t)i * 16 * 256);
        };
        auto ststage = [&]() {
            *(short8*)(&As[sr][sk]) = ra;
            #pragma unroll
            for (int i = 0; i < 8; i++)
                *(short8*)(&Bs[i * 16 + sr][sk]) = rb[i];
        };
        auto compute = [&]() {
            #pragma unroll
            for (int ks = 0; ks < 4; ks++) {
                short8 af = *(const short8*)(&As[mrow][ks * 32 + quad * 8]);
                short8 b0 = *(const short8*)(&Bs[c0 + mrow][ks * 32 + quad * 8]);
                short8 b1 = *(const short8*)(&Bs[c0 + 16 + mrow][ks * 32 + quad * 8]);
                acc0 = __builtin_amdgcn_mfma_f32_16x16x32_bf16(af, b0, acc0, 0, 0, 0);
                acc1 = __builtin_amdgcn_mfma_f32_16x16x32_bf16(af, b1, acc1, 0, 0, 0);
            }
        };

        ldstage(0);
        ststage();
        __syncthreads();
        ldstage(128);
        compute();
        __syncthreads();
        ststage();
        __syncthreads();
        compute();

        const u16* bi = g.gbias[z];
        u16* C = g.gC[z];
        int n0 = c0 + mrow, n1 = n0 + 16;
        float bv0 = bf2f(bi[n0]);
        float bv1 = bf2f(bi[n1]);
        #pragma unroll
        for (int r = 0; r < 4; r++) {
            int row = m0 + quad * 4 + r;
            C[(size_t)row * 128 + n0] = f2bf(seluf(acc0[r] + bv0));
            C[(size_t)row * 128 + n1] = f2bf(seluf(acc1[r] + bv1));
        }
        __syncthreads();
    }
    gbar(g.bar, NBLK * 4);

    // ===== S5: fused pair MLP + loss accumulation ==========================
    for (int vb = bid; vb < 256; vb += NBLK) {
        urow136* Xs = (urow136*)Lraw;
        urow136* Ws = (urow136*)(Lraw + 17408);
        float* wred = (float*)(Lraw + 52224);
        int mrow = lane & 15, quad = lane >> 4;
        int p0 = vb * 64;
        const u16* he = g.gC[0];
        const u16* hp = g.gC[1];

        {
            int row = tid >> 2, sub = tid & 3;
            int b = p0 + row;
            int ia = g.di[b], ic = g.dr[b];
            const uint4* pe = (const uint4*)(he + (size_t)ia * 128 + sub * 32);
            const uint4* pp = (const uint4*)(hp + (size_t)ic * 128 + sub * 32);
            #pragma unroll
            for (int q = 0; q < 4; q++) {
                uint4 ue = pe[q], up = pp[q];
                u32 eu[4] = {ue.x, ue.y, ue.z, ue.w};
                u32 pu[4] = {up.x, up.y, up.z, up.w};
                #pragma unroll
                for (int c = 0; c < 4; c++) {
                    float lo = bf2f((u16)(eu[c] & 0xffffu)) * bf2f((u16)(pu[c] & 0xffffu));
                    float hi = bf2f((u16)(eu[c] >> 16)) * bf2f((u16)(pu[c] >> 16));
                    *(u32*)(&Xs[row][sub * 32 + q * 8 + c * 2]) =
                        (u32)f2bf(lo) | ((u32)f2bf(hi) << 16);
                }
            }
        }
        {
            int n = tid >> 1, half = tid & 1;
            const short8* src = (const short8*)(g.W1T + (size_t)n * 128 + half * 64);
            short8* dst = (short8*)(&Ws[n][half * 64]);
            #pragma unroll
            for (int i = 0; i < 8; i++) dst[i] = src[i];
        }
        __syncthreads();

        f32x4 acc[8];
        #pragma unroll
        for (int nt = 0; nt < 8; nt++) acc[nt] = {0.f, 0.f, 0.f, 0.f};
        #pragma unroll
        for (int ks = 0; ks < 4; ks++) {
            short8 af = *(const short8*)(&Xs[wv * 16 + mrow][ks * 32 + quad * 8]);
            #pragma unroll
            for (int nt = 0; nt < 8; nt++) {
                short8 bfv = *(const short8*)(&Ws[nt * 16 + mrow][ks * 32 + quad * 8]);
                acc[nt] = __builtin_amdgcn_mfma_f32_16x16x32_bf16(af, bfv, acc[nt], 0, 0, 0);
            }
        }
        __syncthreads();
        #pragma unroll
        for (int nt = 0; nt < 8; nt++) {
            int col = nt * 16 + mrow;
            float bv = bf2f(g.mb1_[col]);
            #pragma unroll
            for (int r = 0; r < 4; r++) {
                int row = wv * 16 + quad * 4 + r;
                Xs[row][col] = f2bf(seluf(acc[nt][r] + bv));
            }
        }
        {
            int n = tid >> 1, half = tid & 1;
            const short8* src = (const short8*)(g.W2T + (size_t)n * 128 + half * 64);
            short8* dst = (short8*)(&Ws[n][half * 64]);
            #pragma unroll
            for (int i = 0; i < 8; i++) dst[i] = src[i];
        }
        __syncthreads();

        #pragma unroll
        for (int nt = 0; nt < 8; nt++) acc[nt] = {0.f, 0.f, 0.f, 0.f};
        #pragma unroll
        for (int ks = 0; ks < 4; ks++) {
            short8 af = *(const short8*)(&Xs[wv * 16 + mrow][ks * 32 + quad * 8]);
            #pragma unroll
            for (int nt = 0; nt < 8; nt++) {
                short8 bfv = *(const short8*)(&Ws[nt * 16 + mrow][ks * 32 + quad * 8]);
                acc[nt] = __builtin_amdgcn_mfma_f32_16x16x32_bf16(af, bfv, acc[nt], 0, 0, 0);
            }
        }

        float zp[4] = {0.f, 0.f, 0.f, 0.f};
        #pragma unroll
        for (int nt = 0; nt < 8; nt++) {
            int col = nt * 16 + mrow;
            float bv = bf2f(g.mb2_[col]);
            float wp = bf2f(g.wpred[col]);
            #pragma unroll
            for (int r = 0; r < 4; r++) {
                float x2 = bf2f(f2bf(seluf(acc[nt][r] + bv)));
                zp[r] = fmaf(x2, wp, zp[r]);
            }
        }
        #pragma unroll
        for (int r = 0; r < 4; r++) {
            #pragma unroll
            for (int o = 1; o < 16; o <<= 1) zp[r] += __shfl_xor(zp[r], o, 64);
        }
        float bpv = bf2f(g.bpred[0]);
        float lsum = 0.f;
        #pragma unroll
        for (int r = 0; r < 4; r++) {
            int b = p0 + wv * 16 + quad * 4 + r;
            float z = zp[r] + bpv;
            float sig = 1.f / (1.f + __expf(-z));
            if (mrow == 0) g.out[1 + b] = sig;
            float y = (float)g.labels[b];
            lsum += fmaxf(z, 0.f) - z * y + log1pf(__expf(-fabsf(z)));
        }
        // quad-only butterfly: 16 mrow lanes hold identical lsum
        lsum += __shfl_xor(lsum, 16, 64);
        lsum += __shfl_xor(lsum, 32, 64);
        if (lane == 0) wred[wv] = lsum;
        __syncthreads();
        if (tid == 0) atomicAdd(g.lossacc, wred[0] + wred[1] + wred[2] + wred[3]);
        __syncthreads();
    }
    gbar(g.bar, NBLK * 5);

    // ===== S6: loss finalization ===========================================
    if (bid == 0 && tid == 0) {
        float tot = atomicAdd(g.lossacc, 0.f);
        g.out[0] = tot * (1.f / 16384.f);
    }
}

// ---------------- launch ----------------
extern "C" void kernel_launch(void* const* d_in, const int* in_sizes, int n_in,
                              void* d_out, int out_size, void* d_ws, size_t ws_size,
                              hipStream_t stream) {
    const void* e_p_adj = d_in[0];
    const void* e_e_adj = d_in[1];
    const void* p_p_adj = d_in[2];
    const int* in_dis  = (const int*)d_in[3];
    const int* in_drug = (const int*)d_in[4];
    const int* labels  = (const int*)d_in[5];
    float* out = (float*)d_out;

    char* ws = (char*)d_ws;
    size_t off = 0;
    auto take = [&](size_t bytes) { char* p = ws + off; off = (off + bytes + 255) & ~(size_t)255; return p; };
    u16*   A_e   = (u16*)take((size_t)2048 * 256 * 2);
    u16*   A_p   = (u16*)take((size_t)2048 * 256 * 2);
    u16*   WcTe  = (u16*)take((size_t)128 * 256 * 2);
    u16*   WcTp  = (u16*)take((size_t)128 * 256 * 2);
    u16*   W1T   = (u16*)take((size_t)128 * 128 * 2);
    u16*   W2T   = (u16*)take((size_t)128 * 128 * 2);
    u16*   b_e   = (u16*)take(256);
    u16*   b_p   = (u16*)take(256);
    u16*   h_e   = (u16*)take((size_t)2048 * 128 * 2);
    u16*   h_p   = (u16*)take((size_t)2048 * 128 * 2);
    float* ko_d  = (float*)take((size_t)2048 * 32 * 4);
    float* qs_d  = (float*)take((size_t)2048 * 32 * 4);
    float* ko_p  = (float*)take((size_t)2048 * 32 * 4);
    float* qs_p  = (float*)take((size_t)2048 * 32 * 4);
    float* csd   = (float*)take(128 * 4);
    float* csp   = (float*)take(128 * 4);
    float* lossacc = (float*)take(256);
    u32*   bar   = (u32*)take(256);
    u16*   canon = (u16*)take((size_t)700000 * 2);
    u16*   idx0  = (u16*)take((size_t)2048 * 2048 * 2);
    u16*   idx1  = (u16*)take((size_t)2048 * 2048 * 2);
    u16*   idx2  = (u16*)take((size_t)2048 * 2048 * 2);
    u16*   idx3  = (u16*)take((size_t)2048 * 2048 * 2);
    u32*   cnt0  = (u32*)take(2048 * 4);
    u32*   cnt2  = (u32*)take(2048 * 4);
    u32*   cnt3  = (u32*)take(2048 * 4);
    u32*   cntT  = (u32*)take(2048 * 4);

    const int segidx[NSEG] = {6, 7, 14, 18, 8, 22, 11, 24, 26, 28,
                              15, 16, 17, 19, 20, 21,
                              9, 10, 12, 13, 23, 25, 27, 29, 30, 31};
    const int segn[NSEG]   = {262144, 262144, 8192, 8192, 16384, 16384, 16384, 16384, 16384, 16384,
                              32, 32, 1, 32, 32, 1,
                              128, 128, 128, 128, 128, 128, 128, 128, 128, 1};
    u16* cp[NSEG];
    MG mg;
    {
        int o = 0;
        for (int i = 0; i < NSEG; i++) {
            mg.src[i] = d_in[segidx[i]];
            mg.soff[i] = o;
            mg.sn[i] = segn[i];
            cp[i] = canon + o;
            o += (segn[i] + 15) & ~15;
        }
    }
    u16 *cdemb = cp[0], *cpemb = cp[1], *cWa1d = cp[2], *cWa1p = cp[3];
    u16 *cWdg = cp[4], *cWd2 = cp[5], *cWpg = cp[6], *cWp3 = cp[7];
    u16 *cW1 = cp[8], *cW2 = cp[9];
    u16 *cba1d = cp[10], *cWa2d = cp[11], *cba2d = cp[12];
    u16 *cba1p = cp[13], *cWa2p = cp[14], *cba2p = cp[15];
    u16 *cbdg_lin = cp[16], *cbdg = cp[17], *cbpg_lin = cp[18], *cbpg = cp[19];
    u16 *cbd2 = cp[20], *cbp3 = cp[21], *cmb1 = cp[22], *cmb2 = cp[23];
    u16 *cWpred = cp[24], *cbpred = cp[25];

    mg.adj[0] = e_p_adj; mg.adj[1] = e_e_adj; mg.adj[2] = p_p_adj;
    mg.demb_raw = d_in[6];
    mg.canon = canon;
    mg.ridx[0] = idx0; mg.ridx[1] = idx2; mg.ridx[2] = idx3;
    mg.rcnt[0] = cnt0; mg.rcnt[1] = cnt2; mg.rcnt[2] = cnt3;
    mg.cidx = idx1; mg.ccnt = cntT;
    mg.demb = cdemb; mg.pemb = cpemb;
    mg.Wa1d = cWa1d; mg.ba1d = cba1d; mg.Wa1p = cWa1p; mg.ba1p = cba1p;
    mg.ko_d = ko_d; mg.qs_d = qs_d; mg.ko_p = ko_p; mg.qs_p = qs_p;
    mg.ts[0] = cW1; mg.ts[1] = cW2; mg.ts[2] = cWdg;
    mg.ts[3] = cWd2; mg.ts[4] = cWpg; mg.ts[5] = cWp3;
    mg.W1T = W1T; mg.W2T = W2T; mg.WcTe = WcTe; mg.WcTp = WcTp;
    mg.ba[0] = cbdg_lin; mg.ba[1] = cbdg; mg.ba[2] = cbd2;
    mg.bb[0] = cbpg_lin; mg.bb[1] = cbpg; mg.bb[2] = cbp3;
    mg.b_e = b_e; mg.b_p = b_p; mg.csd = csd; mg.csp = csp;
    mg.avgidx[0] = idx2; mg.avgcnt[0] = cnt2; mg.avgemb[0] = cdemb; mg.avgout[0] = A_e + 128;
    mg.avgidx[1] = idx3; mg.avgcnt[1] = cnt3; mg.avgemb[1] = cpemb; mg.avgout[1] = A_p + 128;
    mg.sidx[0] = idx0; mg.scnt[0] = cnt0; mg.sko[0] = ko_d; mg.sqs[0] = qs_d;
    mg.sw2[0] = cWa2d; mg.sb2[0] = cba2d; mg.semb[0] = cpemb; mg.scs[0] = csp;
    mg.sout[0] = A_e;
    mg.sidx[1] = idx1; mg.scnt[1] = cntT; mg.sko[1] = ko_p; mg.sqs[1] = qs_p;
    mg.sw2[1] = cWa2p; mg.sb2[1] = cba2p; mg.semb[1] = cdemb; mg.scs[1] = csd;
    mg.sout[1] = A_p;
    mg.gA[0] = A_e; mg.gBT[0] = WcTe; mg.gC[0] = h_e; mg.gbias[0] = b_e;
    mg.gA[1] = A_p; mg.gBT[1] = WcTp; mg.gC[1] = h_p; mg.gbias[1] = b_p;
    mg.di = in_dis; mg.dr = in_drug;
    mg.mb1_ = cmb1; mg.mb2_ = cmb2;
    mg.wpred = cWpred; mg.bpred = cbpred; mg.labels = labels;
    mg.out = out; mg.lossacc = lossacc;
    mg.bar = bar;

    initk<<<1, 256, 0, stream>>>(cntT, lossacc, bar);
    mega<<<NBLK, 256, 0, stream>>>(mg);
}

// Round 11
// 225.174 us; speedup vs baseline: 2.1875x; 2.1875x over previous
//
#include <hip/hip_runtime.h>

#define ND   2048
#define BB   16384

typedef unsigned short u16;
typedef unsigned int u32;
typedef __attribute__((ext_vector_type(8))) short short8;
typedef __attribute__((ext_vector_type(4))) float f32x4;

__device__ inline float bf2f(u16 u) {
    union { u32 i; float f; } v; v.i = ((u32)u) << 16; return v.f;
}
__device__ inline u16 f2bf(float f) {
    union { float f; u32 i; } v; v.f = f;
    u32 i = v.i + 0x7fffu + ((v.i >> 16) & 1u);
    return (u16)(i >> 16);
}
__device__ inline float seluf(float x) {
    const float sc = 1.0507009873554805f, al = 1.6732632423543772f;
    return x > 0.f ? sc * x : sc * al * expm1f(x);
}

// ---------------- per-block dtype sniff (deterministic, no cross-block dep) -
__device__ inline bool sniff_f32(const void* demb_raw, void* lds) {
    int tid = threadIdx.x;
    int* redf = (int*)lds;
    const u16* p6 = (const u16*)demb_raw;
    int sane = 0;
    #pragma unroll
    for (int i = 0; i < 2; i++) {
        u16 u = p6[4 * tid + 2 * i];
        int e = (u >> 7) & 0xFF;
        if (u == 0 || (e >= 0x66 && e <= 0x8C)) sane++;
    }
    redf[tid] = sane;
    __syncthreads();
    for (int o = 128; o > 0; o >>= 1) {
        if (tid < o) redf[tid] += redf[tid + o];
        __syncthreads();
    }
    bool f32 = redf[0] < 300;
    __syncthreads();
    return f32;
}

// ---------------- merged: conversion + CSR row lists + zeroing -------------
// blocks [0,1536): csr role, 4 rows/block (m = bx>>9, r0 = (bx&511)*4)
//   blocks [0,8) additionally zero cntT; block 8 zeros lossacc/losscnt
//   (consumed only by LATER dispatches -> stream order suffices)
// blocks [1536,3200): cvt role (seg = idx>>6, 64 blocks/segment), u32-wide
#define NSEG 26
struct CvtArgs { const void* src[NSEG]; int off[NSEG]; int n[NSEG]; };
struct CS {
    const void* adj[3];
    u16* ridx[3]; u32* rcnt[3];
    const void* demb_raw;
    u32* cntT; float* lossacc; u32* losscnt;
};

__global__ __launch_bounds__(256) void cvtcsr(CvtArgs a, u16* __restrict__ base, CS c) {
    int bx = blockIdx.x;
    int t = threadIdx.x;
    __shared__ int sniffbuf[256];
    bool f32 = sniff_f32(c.demb_raw, sniffbuf);
    if (bx < 8) c.cntT[bx * 256 + t] = 0u;
    if (bx == 8 && t == 0) { c.lossacc[0] = 0.f; c.losscnt[0] = 0u; }
    if (bx < 1536) {
        int m = bx >> 9;
        int r0 = (bx & 511) * 4;
        int lane = t & 63;
        __shared__ u32 lcnt[4];
        if (t < 4) lcnt[t] = 0;
        __syncthreads();
        float v[4][8];
        int c0 = t * 8;
        if (f32) {
            #pragma unroll
            for (int rr = 0; rr < 4; rr++) {
                const float4* p = (const float4*)((const float*)c.adj[m] +
                                                  (size_t)(r0 + rr) * 2048 + c0);
                float4 x = p[0], y = p[1];
                v[rr][0] = x.x; v[rr][1] = x.y; v[rr][2] = x.z; v[rr][3] = x.w;
                v[rr][4] = y.x; v[rr][5] = y.y; v[rr][6] = y.z; v[rr][7] = y.w;
            }
        } else {
            #pragma unroll
            for (int rr = 0; rr < 4; rr++) {
                const uint4* p = (const uint4*)((const u16*)c.adj[m] +
                                                (size_t)(r0 + rr) * 2048 + c0);
                uint4 x = p[0];
                u32 u[4] = {x.x, x.y, x.z, x.w};
                #pragma unroll
                for (int i = 0; i < 4; i++) {
                    v[rr][2 * i + 0] = (u[i] & 0xffffu) ? 1.f : 0.f;
                    v[rr][2 * i + 1] = (u[i] >> 16)     ? 1.f : 0.f;
                }
            }
        }
        #pragma unroll
        for (int rr = 0; rr < 4; rr++) {
            int cnt = 0;
            #pragma unroll
            for (int i = 0; i < 8; i++) cnt += (v[rr][i] != 0.f) ? 1 : 0;
            int pfx = cnt;
            #pragma unroll
            for (int o = 1; o < 64; o <<= 1) {
                int s = __shfl_up(pfx, o, 64);
                if (lane >= o) pfx += s;
            }
            int wtot = __shfl(pfx, 63, 64);
            u32 wb = 0;
            if (lane == 0) wb = atomicAdd(&lcnt[rr], (u32)wtot);
            wb = __shfl((int)wb, 0, 64);
            int o = (int)wb + pfx - cnt;
            u16* ridx = c.ridx[m] + (size_t)(r0 + rr) * 2048;
            #pragma unroll
            for (int i = 0; i < 8; i++) {
                if (v[rr][i] != 0.f) ridx[o++] = (u16)(c0 + i);
            }
        }
        __syncthreads();
        if (t < 4) c.rcnt[m][r0 + t] = lcnt[t];
    } else {
        int idx = bx - 1536;
        int seg = idx >> 6, xb = idx & 63;
        int n = a.n[seg];
        const void* s = a.src[seg];
        u16* d = base + a.off[seg];
        int nw = n >> 1;
        if (f32) {
            const float2* sf = (const float2*)s;
            u32* dw = (u32*)d;
            for (int i = xb * 256 + t; i < nw; i += 16384) {
                float2 v = sf[i];
                dw[i] = (u32)f2bf(v.x) | ((u32)f2bf(v.y) << 16);
            }
        } else {
            const u32* sw = (const u32*)s;
            u32* dw = (u32*)d;
            for (int i = xb * 256 + t; i < nw; i += 16384) dw[i] = sw[i];
        }
        if ((n & 1) && xb == 0 && t == 0)
            d[n - 1] = f32 ? f2bf(((const float*)s)[n - 1]) : ((const u16*)s)[n - 1];
    }
}

// ---------------- merged prep ------------------------------------------
// [0,4):        colsum + bias combine
// [4,2052):     colbuild (e_p column lists; ~0.4 entries/thread)
// [2052,3076):  avg aggregation (task = (id>>9): 0=e_e->A_e+128, 1=p_p->A_p+128)
// [3076,4100):  koqs-v2 (8 row-units/block, W staged in LDS)
// [4100,4196):  tpose_smalls (96 tiles)
struct PR {
    const u16* demb; const u16* pemb;
    const u16* Wa1d; const u16* ba1d;
    const u16* Wa1p; const u16* ba1p;
    float* ko_d; float* qs_d; float* ko_p; float* qs_p;
    const u16* idx0; const u32* cnt0; u16* cidx; u32* ccnt;
    const u16* ts[6]; u16* W1T; u16* W2T; u16* WcTe; u16* WcTp;
    const u16* ba[3]; const u16* bb[3]; u16* b_e; u16* b_p;
    float* csd; float* csp;
    const u16* avgidx[2]; const u32* avgcnt[2]; const u16* avgemb[2]; u16* avgout[2];
};

__global__ __launch_bounds__(256) void prep2(PR p) {
    int bx = blockIdx.x;
    int tid = threadIdx.x;
    __shared__ float sx[2][128];
    __shared__ float sred[2][128];
    __shared__ u16 stile[32][33];
    __shared__ float st0[256], st1[256];
    __shared__ u16 Wl[4096];

    if (bx < 4) {
        // ---- colsum (f32) + bias combine; block owns 64 dims of one matrix
        int id = bx;             // 0..3
        int m = id >> 1, half = id & 1;
        const u16* e = m ? p.pemb : p.demb;
        int c2 = tid & 31, rg = tid >> 5;     // 32 dim-pairs x 8 row-groups
        int dbase = half * 64;
        float s0 = 0.f, s1 = 0.f;
        for (int it = 0; it < 256; it++) {
            int row = it * 8 + rg;
            u32 v = *(const u32*)(e + (size_t)row * 128 + dbase + c2 * 2);
            s0 += bf2f((u16)(v & 0xffffu));
            s1 += bf2f((u16)(v >> 16));
        }
        st0[tid] = s0; st1[tid] = s1;
        __syncthreads();
        if (tid < 32) {
            float a0 = 0.f, a1 = 0.f;
            #pragma unroll
            for (int g = 0; g < 8; g++) { a0 += st0[g * 32 + tid]; a1 += st1[g * 32 + tid]; }
            float* cs = m ? p.csp : p.csd;
            cs[dbase + tid * 2 + 0] = a0;
            cs[dbase + tid * 2 + 1] = a1;
        }
        if (tid < 64) {
            int d = dbase + tid;
            if (m == 0)
                p.b_e[d] = f2bf(bf2f(p.ba[0][d]) + bf2f(p.ba[1][d]) + bf2f(p.ba[2][d]));
            else
                p.b_p[d] = f2bf(bf2f(p.bb[0][d]) + bf2f(p.bb[1][d]) + bf2f(p.bb[2][d]));
        }
    } else if (bx < 2052) {
        // ---- colbuild: e_p column lists from row CSR (entry-parallel)
        int r = bx - 4;
        int n = (int)p.cnt0[r];
        const u16* row = p.idx0 + (size_t)r * 2048;
        for (int i = tid; i < n; i += 256) {
            int cc = (int)row[i];
            u32 q = atomicAdd(&p.ccnt[cc], 1u);
            p.cidx[(size_t)cc * 2048 + q] = (u16)r;
        }
    } else if (bx < 3076) {
        // ---- avg aggregation (knn branch): 4 rows per block
        int id = bx - 2052;
        int task = id >> 9, blk = id & 511;
        int wv = tid >> 6, lane = tid & 63;
        int grp = lane >> 4, dim = lane & 15;
        int r = blk * 4 + wv;
        const u16* idx = p.avgidx[task] + (size_t)r * 2048;
        int nnz = (int)p.avgcnt[task][r];
        const u16* emb = p.avgemb[task];
        float acc[8];
        #pragma unroll
        for (int t = 0; t < 8; t++) acc[t] = 0.f;
        for (int base = 0; base < nnz; base += 64) {
            int i = base + lane;
            int j = (i < nnz) ? (int)idx[i] : 0;
            int cend = min(64, nnz - base);
            #pragma unroll 4
            for (int k4 = 0; k4 < cend; k4 += 4) {
                int kk = k4 + grp;
                int jk = __shfl(j, kk, 64);
                float wk = (base + kk < nnz) ? 1.f : 0.f;
                const uint4* pp = (const uint4*)((const char*)emb + jk * 256 + dim * 16);
                uint4 vv = *pp;
                u32 u[4] = {vv.x, vv.y, vv.z, vv.w};
                #pragma unroll
                for (int cc = 0; cc < 4; cc++) {
                    acc[2 * cc + 0] = fmaf(wk, bf2f((u16)(u[cc] & 0xffffu)), acc[2 * cc + 0]);
                    acc[2 * cc + 1] = fmaf(wk, bf2f((u16)(u[cc] >> 16)), acc[2 * cc + 1]);
                }
            }
        }
        #pragma unroll
        for (int t = 0; t < 8; t++) {
            acc[t] += __shfl_xor(acc[t], 32, 64);
            acc[t] += __shfl_xor(acc[t], 16, 64);
        }
        if (grp == 0) {
            float sc = 1.f / ((float)nnz + 1e-8f);
            float v[8];
            #pragma unroll
            for (int t = 0; t < 8; t++) v[t] = acc[t] * sc;
            uint4 pk;
            pk.x = (u32)f2bf(v[0]) | ((u32)f2bf(v[1]) << 16);
            pk.y = (u32)f2bf(v[2]) | ((u32)f2bf(v[3]) << 16);
            pk.z = (u32)f2bf(v[4]) | ((u32)f2bf(v[5]) << 16);
            pk.w = (u32)f2bf(v[6]) | ((u32)f2bf(v[7]) << 16);
            *(uint4*)(p.avgout[task] + (size_t)r * 256 + dim * 8) = pk;
        }
    } else if (bx < 4100) {
        // ---- koqs-v2: 8 row-units per block, W staged in LDS (8 KB)
        int blk = bx - 3076;       // 0..1023
        int m = blk >> 8;          // 256 blocks per matrix m
        int r0 = (blk & 255) * 8;  // 8 rows per block
        const u16* src; const u16* W; const u16* bias; float* out;
        switch (m) {
            case 0:  src = p.pemb; W = p.Wa1d;            bias = nullptr; out = p.ko_d; break;
            case 1:  src = p.demb; W = p.Wa1d + 128 * 32; bias = p.ba1d;  out = p.qs_d; break;
            case 2:  src = p.demb; W = p.Wa1p;            bias = nullptr; out = p.ko_p; break;
            default: src = p.pemb; W = p.Wa1p + 128 * 32; bias = p.ba1p;  out = p.qs_p; break;
        }
        {
            const uint4* wsrc = (const uint4*)W;    // 4096 u16 = 512 uint4
            uint4* wdst = (uint4*)Wl;
            #pragma unroll
            for (int i = 0; i < 2; i++) wdst[i * 256 + tid] = wsrc[i * 256 + tid];
        }
        __syncthreads();
        int sub = tid >> 7, t = tid & 127;
        int a = t & 31, part = t >> 5;
        #pragma unroll 1
        for (int rp = 0; rp < 4; rp++) {
            int row = r0 + rp * 2 + sub;
            sx[sub][t] = bf2f(src[(size_t)row * 128 + t]);
            __syncthreads();
            float s = 0.f;
            #pragma unroll
            for (int k = 0; k < 32; k++)
                s += sx[sub][part * 32 + k] * bf2f(Wl[(part * 32 + k) * 32 + a]);
            sred[sub][t] = s;
            __syncthreads();
            if (part == 0) {
                float tt = sred[sub][a] + sred[sub][a + 32] + sred[sub][a + 64] + sred[sub][a + 96];
                if (bias) tt += bf2f(bias[a]);
                out[(size_t)row * 32 + a] = tt;
            }
            __syncthreads();
        }
    } else {
        // ---- tpose_smalls
        int id = bx - 4100;
        int z = id >> 4, rem = id & 15;
        int c0 = (rem & 3) * 32, r0 = (rem >> 2) * 32;
        const u16* in = p.ts[z];
        u16* out; int ldo, ooff;
        switch (z) {
            case 0:  out = p.W1T;  ldo = 128; ooff = 0;   break;
            case 1:  out = p.W2T;  ldo = 128; ooff = 0;   break;
            case 2:  out = p.WcTe; ldo = 256; ooff = 0;   break;
            case 3:  out = p.WcTe; ldo = 256; ooff = 128; break;
            case 4:  out = p.WcTp; ldo = 256; ooff = 0;   break;
            default: out = p.WcTp; ldo = 256; ooff = 128; break;
        }
        int tx = tid & 31, ty = tid >> 5;
        int x = c0 + tx;
        for (int i = ty; i < 32; i += 8)
            stile[i][tx] = in[(size_t)(r0 + i) * 128 + x];
        __syncthreads();
        int rr = r0 + tx;
        for (int i = ty; i < 32; i += 8)
            out[(size_t)(c0 + i) * ldo + ooff + rr] = stile[tx][i];
    }
}

// ---------------- sparse attention aggregation (2 attn tasks only) ---------
struct SP {
    const u16* idx[2]; const u32* cnt[2];
    const float* ko[2]; const float* qs[2];
    const u16* w2[2]; const u16* b2[2];
    const u16* emb[2]; const float* csum[2];
    u16* out[2];
};

__global__ __launch_bounds__(256) void spagg(SP a) {
    int task = blockIdx.y;
    int tid = threadIdx.x;
    int wv = tid >> 6, lane = tid & 63;
    int grp = lane >> 4, dim = lane & 15;
    int r = blockIdx.x * 4 + wv;
    const u16* idx = a.idx[task] + (size_t)r * 2048;
    int nnz = (int)a.cnt[task][r];
    const u16* emb = a.emb[task];
    const float* ko = a.ko[task];

    float qsr[32], w2h[32];
    {
        const float4* qp = (const float4*)(a.qs[task] + (size_t)r * 32);
        #pragma unroll
        for (int i = 0; i < 8; i++) {
            float4 v = qp[i];
            qsr[4 * i + 0] = v.x; qsr[4 * i + 1] = v.y;
            qsr[4 * i + 2] = v.z; qsr[4 * i + 3] = v.w;
        }
        #pragma unroll
        for (int i = 0; i < 32; i++) w2h[i] = bf2f(a.w2[task][i]);
    }
    float b2v = bf2f(a.b2[task][0]);

    float acc[8];
    #pragma unroll
    for (int t = 0; t < 8; t++) acc[t] = 0.f;
    float wsuml = 0.f;

    for (int base = 0; base < nnz; base += 64) {
        int i = base + lane;
        float w = 0.f;
        int j = 0;
        if (i < nnz) {
            j = (int)idx[i];
            const float4* kp = (const float4*)(ko + (size_t)j * 32);
            float s = 0.f;
            #pragma unroll
            for (int q = 0; q < 8; q++) {
                float4 kv = kp[q];
                s += fmaxf(qsr[4 * q + 0] + kv.x, 0.f) * w2h[4 * q + 0];
                s += fmaxf(qsr[4 * q + 1] + kv.y, 0.f) * w2h[4 * q + 1];
                s += fmaxf(qsr[4 * q + 2] + kv.z, 0.f) * w2h[4 * q + 2];
                s += fmaxf(qsr[4 * q + 3] + kv.w, 0.f) * w2h[4 * q + 3];
            }
            w = __expf(fmaxf(s + b2v, 0.f)) - 1.f;
            wsuml += w;
        }
        int cend = min(64, nnz - base);
        #pragma unroll 4
        for (int k4 = 0; k4 < cend; k4 += 4) {
            int kk = k4 + grp;
            float wk = __shfl(w, kk, 64);
            int jk = __shfl(j, kk, 64);
            const uint4* pp = (const uint4*)((const char*)emb + jk * 256 + dim * 16);
            uint4 vv = *pp;
            u32 u[4] = {vv.x, vv.y, vv.z, vv.w};
            #pragma unroll
            for (int cc = 0; cc < 4; cc++) {
                acc[2 * cc + 0] = fmaf(wk, bf2f((u16)(u[cc] & 0xffffu)), acc[2 * cc + 0]);
                acc[2 * cc + 1] = fmaf(wk, bf2f((u16)(u[cc] >> 16)), acc[2 * cc + 1]);
            }
        }
    }

    #pragma unroll
    for (int t = 0; t < 8; t++) {
        acc[t] += __shfl_xor(acc[t], 32, 64);
        acc[t] += __shfl_xor(acc[t], 16, 64);
    }
    #pragma unroll
    for (int o = 32; o > 0; o >>= 1) wsuml += __shfl_xor(wsuml, o, 64);

    if (grp == 0) {
        float sc = 1.f / (2048.f + wsuml);
        const float* cs = a.csum[task] + dim * 8;
        float v[8];
        #pragma unroll
        for (int t = 0; t < 8; t++) v[t] = (cs[t] + acc[t]) * sc;
        uint4 pk;
        pk.x = (u32)f2bf(v[0]) | ((u32)f2bf(v[1]) << 16);
        pk.y = (u32)f2bf(v[2]) | ((u32)f2bf(v[3]) << 16);
        pk.z = (u32)f2bf(v[4]) | ((u32)f2bf(v[5]) << 16);
        pk.w = (u32)f2bf(v[6]) | ((u32)f2bf(v[7]) << 16);
        *(uint4*)(a.out[task] + (size_t)r * 256 + dim * 8) = pk;
    }
}

// ---------------- MFMA GEMM: canonical LDS-tiled (combine stage) -----------
struct GD4 {
    const void* A[4]; const u16* BT[4]; u16* C[4];
    const u16* bias[4]; const float* rs[4];
    int lda[4], ldb[4], ldc[4], coff[4], kiters[4], act[4], araw[4], rsmode[4];
};

#define PADK 136

__global__ __launch_bounds__(256, 2) void gemmL(GD4 g) {
    __shared__ __align__(16) u16 As[16][PADK];
    __shared__ __align__(16) u16 Bs[128][PADK];
    int z = blockIdx.y;
    const void* A = g.A[z];
    const u16* BT = g.BT[z];
    int lda = g.lda[z], ldb = g.ldb[z];
    int kiters = g.kiters[z];
    int tid = threadIdx.x;
    int lane = tid & 63, wv = tid >> 6;
    int mrow = lane & 15, quad = lane >> 4;
    int m0 = blockIdx.x * 16;
    int c0 = wv * 32;
    int sr = tid >> 4, sk = (tid & 15) * 8;
    f32x4 acc0 = {0.f, 0.f, 0.f, 0.f}, acc1 = {0.f, 0.f, 0.f, 0.f};

    short8 ra, rb[8];
    auto ldstage = [&](int kb) {
        ra = *(const short8*)((const u16*)A + (size_t)(m0 + sr) * lda + kb + sk);
        const u16* bbase = BT + (size_t)sr * ldb + kb + sk;
        #pragma unroll
        for (int i = 0; i < 8; i++)
            rb[i] = *(const short8*)(bbase + (size_t)i * 16 * ldb);
    };
    auto ststage = [&]() {
        *(short8*)(&As[sr][sk]) = ra;
        #pragma unroll
        for (int i = 0; i < 8; i++)
            *(short8*)(&Bs[i * 16 + sr][sk]) = rb[i];
    };
    auto compute = [&]() {
        #pragma unroll
        for (int ks = 0; ks < 4; ks++) {
            short8 af = *(const short8*)(&As[mrow][ks * 32 + quad * 8]);
            short8 b0 = *(const short8*)(&Bs[c0 + mrow][ks * 32 + quad * 8]);
            short8 b1 = *(const short8*)(&Bs[c0 + 16 + mrow][ks * 32 + quad * 8]);
            acc0 = __builtin_amdgcn_mfma_f32_16x16x32_bf16(af, b0, acc0, 0, 0, 0);
            acc1 = __builtin_amdgcn_mfma_f32_16x16x32_bf16(af, b1, acc1, 0, 0, 0);
        }
    };

    ldstage(0);
    #pragma unroll 1
    for (int it = 0; it < kiters - 1; ++it) {
        ststage();
        __syncthreads();
        ldstage((it + 1) * 128);
        compute();
        __syncthreads();
    }
    ststage();
    __syncthreads();
    compute();

    const float* rs = g.rs[z];
    int rsmode = g.rsmode[z];
    const u16* bi = g.bias[z];
    u16* C = g.C[z];
    int ldc = g.ldc[z], coff = g.coff[z], act = g.act[z];
    int n0 = c0 + mrow, n1 = n0 + 16;
    float bv0 = bi ? bf2f(bi[n0]) : 0.f;
    float bv1 = bi ? bf2f(bi[n1]) : 0.f;
    #pragma unroll
    for (int r = 0; r < 4; r++) {
        int row = m0 + quad * 4 + r;
        float v0 = acc0[r], v1 = acc1[r];
        if (rsmode == 1) { float sc = rs[row]; v0 *= sc; v1 *= sc; }
        else if (rsmode == 2) {
            float t = 0.f;
            #pragma unroll
            for (int p = 0; p < 8; p++) t += rs[row + p * 2048];
            float sc = 1.f / t;
            v0 *= sc; v1 *= sc;
        }
        v0 += bv0; v1 += bv1;
        if (act) { v0 = seluf(v0); v1 = seluf(v1); }
        C[(size_t)row * ldc + coff + n0] = f2bf(v0);
        C[(size_t)row * ldc + coff + n1] = f2bf(v1);
    }
}

// ---------------- fused pair MLP + loss finalization -----------------------
#define PADX 136
__global__ __launch_bounds__(256, 2) void mlpfused(
    const u16* __restrict__ he, const u16* __restrict__ hp,
    const int* __restrict__ di, const int* __restrict__ dr,
    const u16* __restrict__ W1T, const u16* __restrict__ b1,
    const u16* __restrict__ W2T, const u16* __restrict__ b2,
    const u16* __restrict__ wpred, const u16* __restrict__ bpred,
    const int* __restrict__ labels,
    float* __restrict__ out, float* __restrict__ lossacc,
    u32* __restrict__ losscnt) {
    __shared__ __align__(16) u16 Xs[64][PADX];
    __shared__ __align__(16) u16 Ws[128][PADX];
    __shared__ float wred[4];
    int tid = threadIdx.x;
    int lane = tid & 63, wv = tid >> 6;
    int mrow = lane & 15, quad = lane >> 4;
    int p0 = blockIdx.x * 64;

    {
        int row = tid >> 2, sub = tid & 3;
        int b = p0 + row;
        int ia = di[b], ic = dr[b];
        const uint4* pe = (const uint4*)(he + (size_t)ia * 128 + sub * 32);
        const uint4* pp = (const uint4*)(hp + (size_t)ic * 128 + sub * 32);
        #pragma unroll
        for (int q = 0; q < 4; q++) {
            uint4 ue = pe[q], up = pp[q];
            u32 eu[4] = {ue.x, ue.y, ue.z, ue.w};
            u32 pu[4] = {up.x, up.y, up.z, up.w};
            #pragma unroll
            for (int c = 0; c < 4; c++) {
                float lo = bf2f((u16)(eu[c] & 0xffffu)) * bf2f((u16)(pu[c] & 0xffffu));
                float hi = bf2f((u16)(eu[c] >> 16)) * bf2f((u16)(pu[c] >> 16));
                *(u32*)(&Xs[row][sub * 32 + q * 8 + c * 2]) =
                    (u32)f2bf(lo) | ((u32)f2bf(hi) << 16);
            }
        }
    }
    {
        int n = tid >> 1, half = tid & 1;
        const short8* src = (const short8*)(W1T + (size_t)n * 128 + half * 64);
        short8* dst = (short8*)(&Ws[n][half * 64]);
        #pragma unroll
        for (int i = 0; i < 8; i++) dst[i] = src[i];
    }
    __syncthreads();

    f32x4 acc[8];
    #pragma unroll
    for (int nt = 0; nt < 8; nt++) acc[nt] = {0.f, 0.f, 0.f, 0.f};
    #pragma unroll
    for (int ks = 0; ks < 4; ks++) {
        short8 af = *(const short8*)(&Xs[wv * 16 + mrow][ks * 32 + quad * 8]);
        #pragma unroll
        for (int nt = 0; nt < 8; nt++) {
            short8 bfv = *(const short8*)(&Ws[nt * 16 + mrow][ks * 32 + quad * 8]);
            acc[nt] = __builtin_amdgcn_mfma_f32_16x16x32_bf16(af, bfv, acc[nt], 0, 0, 0);
        }
    }
    __syncthreads();
    #pragma unroll
    for (int nt = 0; nt < 8; nt++) {
        int col = nt * 16 + mrow;
        float bv = bf2f(b1[col]);
        #pragma unroll
        for (int r = 0; r < 4; r++) {
            int row = wv * 16 + quad * 4 + r;
            Xs[row][col] = f2bf(seluf(acc[nt][r] + bv));
        }
    }
    {
        int n = tid >> 1, half = tid & 1;
        const short8* src = (const short8*)(W2T + (size_t)n * 128 + half * 64);
        short8* dst = (short8*)(&Ws[n][half * 64]);
        #pragma unroll
        for (int i = 0; i < 8; i++) dst[i] = src[i];
    }
    __syncthreads();

    #pragma unroll
    for (int nt = 0; nt < 8; nt++) acc[nt] = {0.f, 0.f, 0.f, 0.f};
    #pragma unroll
    for (int ks = 0; ks < 4; ks++) {
        short8 af = *(const short8*)(&Xs[wv * 16 + mrow][ks * 32 + quad * 8]);
        #pragma unroll
        for (int nt = 0; nt < 8; nt++) {
            short8 bfv = *(const short8*)(&Ws[nt * 16 + mrow][ks * 32 + quad * 8]);
            acc[nt] = __builtin_amdgcn_mfma_f32_16x16x32_bf16(af, bfv, acc[nt], 0, 0, 0);
        }
    }

    float zp[4] = {0.f, 0.f, 0.f, 0.f};
    #pragma unroll
    for (int nt = 0; nt < 8; nt++) {
        int col = nt * 16 + mrow;
        float bv = bf2f(b2[col]);
        float wp = bf2f(wpred[col]);
        #pragma unroll
        for (int r = 0; r < 4; r++) {
            float x2 = bf2f(f2bf(seluf(acc[nt][r] + bv)));
            zp[r] = fmaf(x2, wp, zp[r]);
        }
    }
    #pragma unroll
    for (int r = 0; r < 4; r++) {
        #pragma unroll
        for (int o = 1; o < 16; o <<= 1) zp[r] += __shfl_xor(zp[r], o, 64);
    }
    float bpv = bf2f(bpred[0]);
    float lsum = 0.f;
    #pragma unroll
    for (int r = 0; r < 4; r++) {
        int b = p0 + wv * 16 + quad * 4 + r;
        float z = zp[r] + bpv;
        float sig = 1.f / (1.f + __expf(-z));
        if (mrow == 0) out[1 + b] = sig;
        float y = (float)labels[b];
        lsum += fmaxf(z, 0.f) - z * y + log1pf(__expf(-fabsf(z)));
    }
    // quad-only butterfly: 16 mrow lanes hold identical lsum (zp reduced over
    // mrow), so the result is the exact 16-row wave sum on every lane.
    lsum += __shfl_xor(lsum, 16, 64);
    lsum += __shfl_xor(lsum, 32, 64);
    if (lane == 0) wred[wv] = lsum;
    __syncthreads();
    if (tid == 0) {
        float bs = wred[0] + wred[1] + wred[2] + wred[3];
        atomicAdd(lossacc, bs);
        __threadfence();
        u32 old = atomicAdd(losscnt, 1u);
        if (old == 255u) {
            float tot = atomicAdd(lossacc, 0.f);
            out[0] = tot * (1.f / 16384.f);
        }
    }
}

// ---------------- launch ----------------
extern "C" void kernel_launch(void* const* d_in, const int* in_sizes, int n_in,
                              void* d_out, int out_size, void* d_ws, size_t ws_size,
                              hipStream_t stream) {
    const void* e_p_adj = d_in[0];
    const void* e_e_adj = d_in[1];
    const void* p_p_adj = d_in[2];
    const int* in_dis  = (const int*)d_in[3];
    const int* in_drug = (const int*)d_in[4];
    const int* labels  = (const int*)d_in[5];
    float* out = (float*)d_out;

    // -------- workspace layout --------
    char* ws = (char*)d_ws;
    size_t off = 0;
    auto take = [&](size_t bytes) { char* p = ws + off; off = (off + bytes + 255) & ~(size_t)255; return p; };
    u16*   A_e   = (u16*)take((size_t)2048 * 256 * 2);
    u16*   A_p   = (u16*)take((size_t)2048 * 256 * 2);
    u16*   WcTe  = (u16*)take((size_t)128 * 256 * 2);
    u16*   WcTp  = (u16*)take((size_t)128 * 256 * 2);
    u16*   W1T   = (u16*)take((size_t)128 * 128 * 2);
    u16*   W2T   = (u16*)take((size_t)128 * 128 * 2);
    u16*   b_e   = (u16*)take(256);
    u16*   b_p   = (u16*)take(256);
    u16*   h_e   = (u16*)take((size_t)2048 * 128 * 2);
    u16*   h_p   = (u16*)take((size_t)2048 * 128 * 2);
    float* ko_d  = (float*)take((size_t)2048 * 32 * 4);
    float* qs_d  = (float*)take((size_t)2048 * 32 * 4);
    float* ko_p  = (float*)take((size_t)2048 * 32 * 4);
    float* qs_p  = (float*)take((size_t)2048 * 32 * 4);
    float* csd   = (float*)take(128 * 4);
    float* csp   = (float*)take(128 * 4);
    float* lossacc = (float*)take(256);
    u32*   losscnt = (u32*)((char*)lossacc + 4);
    u16*   canon = (u16*)take((size_t)700000 * 2);
    u16*   idx0  = (u16*)take((size_t)2048 * 2048 * 2);  // e_p rows (disease)
    u16*   idx1  = (u16*)take((size_t)2048 * 2048 * 2);  // e_p cols (drug)
    u16*   idx2  = (u16*)take((size_t)2048 * 2048 * 2);  // e_e rows
    u16*   idx3  = (u16*)take((size_t)2048 * 2048 * 2);  // p_p rows
    u32*   cnt0  = (u32*)take(2048 * 4);
    u32*   cnt2  = (u32*)take(2048 * 4);
    u32*   cnt3  = (u32*)take(2048 * 4);
    u32*   cntT  = (u32*)take(2048 * 4);                 // e_p col counts

    // -------- canonical parameter table --------
    const int segidx[NSEG] = {6, 7, 14, 18, 8, 22, 11, 24, 26, 28,
                              15, 16, 17, 19, 20, 21,
                              9, 10, 12, 13, 23, 25, 27, 29, 30, 31};
    const int segn[NSEG]   = {262144, 262144, 8192, 8192, 16384, 16384, 16384, 16384, 16384, 16384,
                              32, 32, 1, 32, 32, 1,
                              128, 128, 128, 128, 128, 128, 128, 128, 128, 1};
    CvtArgs ca;
    u16* cp[NSEG];
    {
        int o = 0;
        for (int i = 0; i < NSEG; i++) {
            ca.src[i] = d_in[segidx[i]];
            ca.off[i] = o;
            ca.n[i] = segn[i];
            cp[i] = canon + o;
            o += (segn[i] + 15) & ~15;
        }
    }
    u16 *cdemb = cp[0], *cpemb = cp[1], *cWa1d = cp[2], *cWa1p = cp[3];
    u16 *cWdg = cp[4], *cWd2 = cp[5], *cWpg = cp[6], *cWp3 = cp[7];
    u16 *cW1 = cp[8], *cW2 = cp[9];
    u16 *cba1d = cp[10], *cWa2d = cp[11], *cba2d = cp[12];
    u16 *cba1p = cp[13], *cWa2p = cp[14], *cba2p = cp[15];
    u16 *cbdg_lin = cp[16], *cbdg = cp[17], *cbpg_lin = cp[18], *cbpg = cp[19];
    u16 *cbd2 = cp[20], *cbp3 = cp[21], *cmb1 = cp[22], *cmb2 = cp[23];
    u16 *cWpred = cp[24], *cbpred = cp[25];

    // -------- 1. merged conversion + CSR row lists + zeroing --------
    {
        CS cs;
        cs.adj[0] = e_p_adj; cs.ridx[0] = idx0; cs.rcnt[0] = cnt0;
        cs.adj[1] = e_e_adj; cs.ridx[1] = idx2; cs.rcnt[1] = cnt2;
        cs.adj[2] = p_p_adj; cs.ridx[2] = idx3; cs.rcnt[2] = cnt3;
        cs.demb_raw = d_in[6];
        cs.cntT = cntT; cs.lossacc = lossacc; cs.losscnt = losscnt;
        cvtcsr<<<1536 + 64 * NSEG, 256, 0, stream>>>(ca, canon, cs);
    }

    // -------- 2. merged prep (colsum + colbuild + avg-agg + koqs + tpose) ---
    PR pr;
    pr.demb = cdemb; pr.pemb = cpemb;
    pr.Wa1d = cWa1d; pr.ba1d = cba1d; pr.Wa1p = cWa1p; pr.ba1p = cba1p;
    pr.ko_d = ko_d; pr.qs_d = qs_d; pr.ko_p = ko_p; pr.qs_p = qs_p;
    pr.idx0 = idx0; pr.cnt0 = cnt0; pr.cidx = idx1; pr.ccnt = cntT;
    pr.ts[0] = cW1; pr.ts[1] = cW2; pr.ts[2] = cWdg;
    pr.ts[3] = cWd2; pr.ts[4] = cWpg; pr.ts[5] = cWp3;
    pr.W1T = W1T; pr.W2T = W2T; pr.WcTe = WcTe; pr.WcTp = WcTp;
    pr.ba[0] = cbdg_lin; pr.ba[1] = cbdg; pr.ba[2] = cbd2;
    pr.bb[0] = cbpg_lin; pr.bb[1] = cbpg; pr.bb[2] = cbp3;
    pr.b_e = b_e; pr.b_p = b_p; pr.csd = csd; pr.csp = csp;
    pr.avgidx[0] = idx2; pr.avgcnt[0] = cnt2; pr.avgemb[0] = cdemb; pr.avgout[0] = A_e + 128;
    pr.avgidx[1] = idx3; pr.avgcnt[1] = cnt3; pr.avgemb[1] = cpemb; pr.avgout[1] = A_p + 128;
    prep2<<<4196, 256, 0, stream>>>(pr);

    // -------- 3. sparse attention aggregation (2 tasks) --------
    {
        SP sp;
        sp.idx[0] = idx0; sp.cnt[0] = cnt0; sp.ko[0] = ko_d; sp.qs[0] = qs_d;
        sp.w2[0] = cWa2d; sp.b2[0] = cba2d; sp.emb[0] = cpemb; sp.csum[0] = csp;
        sp.out[0] = A_e;
        sp.idx[1] = idx1; sp.cnt[1] = cntT; sp.ko[1] = ko_p; sp.qs[1] = qs_p;
        sp.w2[1] = cWa2p; sp.b2[1] = cba2p; sp.emb[1] = cdemb; sp.csum[1] = csd;
        sp.out[1] = A_p;
        spagg<<<dim3(512, 2), 256, 0, stream>>>(sp);
    }

    auto setd = [](GD4& g, int z, const void* A, int lda, const u16* BT, int ldb,
                   u16* C, int ldc, int coff, int ki, const u16* bi,
                   const float* rs, int act, int araw, int rm) {
        g.A[z] = A; g.lda[z] = lda; g.BT[z] = BT; g.ldb[z] = ldb;
        g.C[z] = C; g.ldc[z] = ldc; g.coff[z] = coff; g.kiters[z] = ki;
        g.bias[z] = bi; g.rs[z] = rs; g.act[z] = act; g.araw[z] = araw; g.rsmode[z] = rm;
    };

    // -------- 4. combine GEMMs (bias + SELU), batched ----------------------
    {
        GD4 g;
        setd(g, 0, A_e, 256, WcTe, 256, h_e, 128, 0, 2, b_e, nullptr, 1, 0, 0);
        setd(g, 1, A_p, 256, WcTp, 256, h_p, 128, 0, 2, b_p, nullptr, 1, 0, 0);
        setd(g, 2, A_e, 256, WcTe, 256, h_e, 128, 0, 2, b_e, nullptr, 1, 0, 0);
        setd(g, 3, A_e, 256, WcTe, 256, h_e, 128, 0, 2, b_e, nullptr, 1, 0, 0);
        gemmL<<<dim3(128, 2), 256, 0, stream>>>(g);
    }

    // -------- 5. fused pair MLP + loss --------
    mlpfused<<<256, 256, 0, stream>>>(h_e, h_p, in_dis, in_drug,
                                      W1T, cmb1, W2T, cmb2,
                                      cWpred, cbpred, labels, out,
                                      lossacc, losscnt);
}